// Round 1
// baseline (905.346 us; speedup 1.0000x reference)
//
#include <hip/hip_runtime.h>
#include <hip/hip_bf16.h>

#define BATCH 4
#define CCH   64
#define HH    256
#define WW    256
#define HWSZ  65536

typedef unsigned short ushort_t;
typedef unsigned int   uint_t;

static __device__ __forceinline__ ushort_t f2bf(float f) {
    uint_t u = __float_as_uint(f);
    uint_t r = (u + 0x7fffu + ((u >> 16) & 1u)) >> 16;   // RNE
    return (ushort_t)r;
}

// ---------------- K1: conv1x1 64->64, fp32 ----------------
__global__ __launch_bounds__(256) void k1_conv1x1(
    const float* __restrict__ x, const float* __restrict__ w_in,
    float* __restrict__ out0)
{
    __shared__ float xs[64][64];
    int b   = blockIdx.x >> 10;            // 1024 tiles per batch (HW/64)
    int hw0 = (blockIdx.x & 1023) << 6;
    const float* xb = x + ((size_t)b * CCH) * HWSZ + hw0;

    for (int idx = threadIdx.x; idx < 1024; idx += 256) {
        int i = idx >> 4, p4 = (idx & 15) << 2;
        *(float4*)&xs[i][p4] = *(const float4*)(xb + (size_t)i * HWSZ + p4);
    }
    __syncthreads();

    int p  = threadIdx.x & 63;
    int og = __builtin_amdgcn_readfirstlane(threadIdx.x >> 6);  // wave-uniform
    float acc[16];
#pragma unroll
    for (int oo = 0; oo < 16; oo++) acc[oo] = 0.f;

#pragma unroll 8
    for (int i = 0; i < 64; i++) {
        float xv = xs[i][p];
#pragma unroll
        for (int oo = 0; oo < 16; oo++)
            acc[oo] += w_in[(og * 16 + oo) * 64 + i] * xv;   // scalar loads
    }
    float* ob = out0 + ((size_t)b * CCH) * HWSZ + hw0;
#pragma unroll
    for (int oo = 0; oo < 16; oo++)
        ob[(size_t)(og * 16 + oo) * HWSZ + p] = acc[oo];
}

// ---------------- K2v: vertical scans (down fwd, up bwd) -> bf16 ----------------
__global__ __launch_bounds__(256) void k2_vert(
    const float* __restrict__ src,
    const float* __restrict__ w_up, const float* __restrict__ b_up,
    const float* __restrict__ w_dn, const float* __restrict__ b_dn,
    ushort_t* __restrict__ up, ushort_t* __restrict__ down)
{
    int bc = blockIdx.x;            // b*64 + c
    int c  = bc & 63;
    size_t base = (size_t)bc * HWSZ + threadIdx.x;
    const float* s = src + base;
    ushort_t* d = down + base;
    ushort_t* u = up + base;
    float wd = w_dn[c], bd = b_dn[c], wu = w_up[c], bu = b_up[c];

    float h = 0.f;
#pragma unroll 4
    for (int i = 0; i < HH; i++) {
        float v = s[i * WW];
        h = fmaxf(0.f, fmaf(wd, h, v + bd));
        d[i * WW] = f2bf(h);
    }
    h = 0.f;
#pragma unroll 4
    for (int i = HH - 1; i >= 0; i--) {
        float v = s[i * WW];
        h = fmaxf(0.f, fmaf(wu, h, v + bu));
        u[i * WW] = f2bf(h);
    }
}

// ---------------- K2h: horizontal scans (right fwd, left bwd) -> bf16 ----------------
__global__ __launch_bounds__(256) void k2_horiz(
    const float* __restrict__ src,
    const float* __restrict__ w_r, const float* __restrict__ b_r,
    const float* __restrict__ w_l, const float* __restrict__ b_l,
    ushort_t* __restrict__ right, ushort_t* __restrict__ left)
{
    int bc = blockIdx.x;
    int c  = bc & 63;
    size_t rowbase = (size_t)bc * HWSZ + (size_t)threadIdx.x * WW;
    const float* s = src + rowbase;
    float wr = w_r[c], br = b_r[c], wl = w_l[c], bl = b_l[c];

    float h = 0.f;
    for (int ch = 0; ch < 32; ch++) {
        float4 A = *(const float4*)(s + ch * 8);
        float4 Bv = *(const float4*)(s + ch * 8 + 4);
        float vv[8] = {A.x, A.y, A.z, A.w, Bv.x, Bv.y, Bv.z, Bv.w};
        ushort_t us[8];
#pragma unroll
        for (int j = 0; j < 8; j++) {
            h = fmaxf(0.f, fmaf(wr, h, vv[j] + br));
            us[j] = f2bf(h);
        }
        uint4 pk;
        pk.x = (uint_t)us[0] | ((uint_t)us[1] << 16);
        pk.y = (uint_t)us[2] | ((uint_t)us[3] << 16);
        pk.z = (uint_t)us[4] | ((uint_t)us[5] << 16);
        pk.w = (uint_t)us[6] | ((uint_t)us[7] << 16);
        *(uint4*)(right + rowbase + ch * 8) = pk;
    }
    h = 0.f;
    for (int ch = 31; ch >= 0; ch--) {
        float4 A = *(const float4*)(s + ch * 8);
        float4 Bv = *(const float4*)(s + ch * 8 + 4);
        float vv[8] = {A.x, A.y, A.z, A.w, Bv.x, Bv.y, Bv.z, Bv.w};
        ushort_t us[8];
#pragma unroll
        for (int j = 7; j >= 0; j--) {
            h = fmaxf(0.f, fmaf(wl, h, vv[j] + bl));
            us[j] = f2bf(h);
        }
        uint4 pk;
        pk.x = (uint_t)us[0] | ((uint_t)us[1] << 16);
        pk.y = (uint_t)us[2] | ((uint_t)us[3] << 16);
        pk.z = (uint_t)us[4] | ((uint_t)us[5] << 16);
        pk.w = (uint_t)us[6] | ((uint_t)us[7] << 16);
        *(uint4*)(left + rowbase + ch * 8) = pk;
    }
}

// ---------------- K3: stage-3 mix  out3 = relu(sum_dir Wdir @ dir) ----------------
__global__ __launch_bounds__(256) void k3_mix(
    const ushort_t* __restrict__ up, const ushort_t* __restrict__ right,
    const ushort_t* __restrict__ down, const ushort_t* __restrict__ left,
    const float* __restrict__ wD2, float* __restrict__ out3)
{
    __shared__ float xs[64][64];
    int b   = blockIdx.x >> 10;
    int hw0 = (blockIdx.x & 1023) << 6;
    int p   = threadIdx.x & 63;
    int og  = __builtin_amdgcn_readfirstlane(threadIdx.x >> 6);

    float acc[16];
#pragma unroll
    for (int oo = 0; oo < 16; oo++) acc[oo] = 0.f;

    const ushort_t* dirs[4] = {up, right, down, left};
#pragma unroll
    for (int dir = 0; dir < 4; dir++) {
        const ushort_t* db = dirs[dir] + (size_t)b * CCH * HWSZ + hw0;
        __syncthreads();
        for (int idx = threadIdx.x; idx < 2048; idx += 256) {
            int i = idx >> 5, p2 = (idx & 31) << 1;
            uint_t uu = *(const uint_t*)(db + (size_t)i * HWSZ + p2);
            xs[i][p2]     = __uint_as_float(uu << 16);
            xs[i][p2 + 1] = __uint_as_float(uu & 0xffff0000u);
        }
        __syncthreads();
        const float* wrow = wD2 + dir * 64;
#pragma unroll 8
        for (int i = 0; i < 64; i++) {
            float xv = xs[i][p];
#pragma unroll
            for (int oo = 0; oo < 16; oo++)
                acc[oo] += wrow[(og * 16 + oo) * 256 + i] * xv;  // scalar loads
        }
    }
    float* ob = out3 + (size_t)b * CCH * HWSZ + hw0;
#pragma unroll
    for (int oo = 0; oo < 16; oo++)
        ob[(size_t)(og * 16 + oo) * HWSZ + p] = fmaxf(acc[oo], 0.f);
}

// ---------------- K4/K5: 3x3 conv (IC -> 32), bias + relu ----------------
template <int IC>
__global__ __launch_bounds__(256) void conv3x3(
    const float* __restrict__ in, const float* __restrict__ wt,
    const float* __restrict__ bias, float* __restrict__ out)
{
    __shared__ float tile[8][10][34];
    int bi = blockIdx.x;              // b*256 + th*8 + tw  (th<32, tw<8)
    int b  = bi >> 8;
    int th = (bi >> 3) & 31;
    int tw = bi & 7;
    int h0 = th * 8, w0 = tw * 32;
    int tx = threadIdx.x & 31, ty = threadIdx.x >> 5;

    float acc[32];
#pragma unroll
    for (int oc = 0; oc < 32; oc++) acc[oc] = 0.f;

    for (int ic0 = 0; ic0 < IC; ic0 += 8) {
        __syncthreads();
        for (int idx = threadIdx.x; idx < 8 * 10 * 34; idx += 256) {
            int ic = idx / 340;
            int rem = idx - ic * 340;
            int y = rem / 34;
            int xw = rem - y * 34;
            int gh = h0 + y - 1, gw = w0 + xw - 1;
            float v = 0.f;
            if ((unsigned)gh < 256u && (unsigned)gw < 256u)
                v = in[(((size_t)b * IC + ic0 + ic) * 256 + gh) * 256 + gw];
            tile[ic][y][xw] = v;
        }
        __syncthreads();

        for (int ic = 0; ic < 8; ic++) {
            float v[3][3];
#pragma unroll
            for (int dy = 0; dy < 3; dy++)
#pragma unroll
                for (int dx = 0; dx < 3; dx++)
                    v[dy][dx] = tile[ic][ty + dy][tx + dx];
            const float* wbase = wt + ((size_t)(ic0 + ic)) * 9;
#pragma unroll
            for (int oc = 0; oc < 32; oc++) {
                const float* wp = wbase + (size_t)oc * IC * 9;   // uniform -> s_load
#pragma unroll
                for (int k = 0; k < 9; k++)
                    acc[oc] += wp[k] * v[k / 3][k % 3];
            }
        }
    }
#pragma unroll
    for (int oc = 0; oc < 32; oc++) {
        float r = fmaxf(acc[oc] + bias[oc], 0.f);
        out[(((size_t)b * 32 + oc) * 256 + h0 + ty) * 256 + w0 + tx] = r;
    }
}

// ---------------- K6: 1x1 (32->1) + sigmoid gate, out = relu(x*g) ----------------
__global__ __launch_bounds__(256) void k6_gate(
    const float* __restrict__ a2, const float* __restrict__ a3w,
    const float* __restrict__ a3b, const float* __restrict__ x,
    float* __restrict__ out)
{
    int pix = blockIdx.x * 256 + threadIdx.x;    // N = 262144
    int b = pix >> 16;
    int hw = pix & 65535;
    float s = a3b[0];
#pragma unroll
    for (int ic = 0; ic < 32; ic++)
        s += a3w[ic] * a2[((size_t)b * 32 + ic) * HWSZ + hw];
    float g = 1.f / (1.f + __expf(-s));
    const float* xb = x + (size_t)b * CCH * HWSZ + hw;
    float* ob = out + (size_t)b * CCH * HWSZ + hw;
#pragma unroll 8
    for (int c = 0; c < 64; c++)
        ob[(size_t)c * HWSZ] = fmaxf(0.f, xb[(size_t)c * HWSZ] * g);
}

extern "C" void kernel_launch(void* const* d_in, const int* in_sizes, int n_in,
                              void* d_out, int out_size, void* d_ws, size_t ws_size,
                              hipStream_t stream)
{
    const float* x     = (const float*)d_in[0];
    const float* w_in  = (const float*)d_in[1];
    const float* w_up  = (const float*)d_in[2];
    const float* b_up  = (const float*)d_in[3];
    const float* w_rt  = (const float*)d_in[4];
    const float* b_rt  = (const float*)d_in[5];
    const float* w_dn  = (const float*)d_in[6];
    const float* b_dn  = (const float*)d_in[7];
    const float* w_lf  = (const float*)d_in[8];
    const float* b_lf  = (const float*)d_in[9];
    const float* wD2   = (const float*)d_in[10];
    const float* a1w   = (const float*)d_in[11];
    const float* a1b   = (const float*)d_in[12];
    const float* a2w   = (const float*)d_in[13];
    const float* a2b   = (const float*)d_in[14];
    const float* a3w   = (const float*)d_in[15];
    const float* a3b   = (const float*)d_in[16];
    float* out = (float*)d_out;

    char* ws = (char*)d_ws;
    float*    out0  = (float*)ws;                         // 64 MB  [0,64)
    ushort_t* up    = (ushort_t*)(ws + (64ull  << 20));   // 32 MB  [64,96)
    ushort_t* down  = (ushort_t*)(ws + (96ull  << 20));   // 32 MB  [96,128)
    ushort_t* right = (ushort_t*)(ws + (128ull << 20));   // 32 MB  [128,160)
    ushort_t* left  = (ushort_t*)(ws + (160ull << 20));   // 32 MB  [160,192)
    float* out3 = out0;                                   // reuse (out0 dead after K2)
    float* a1   = (float*)(ws + (64ull << 20));           // reuse up region (dead after K3)
    float* a2   = (float*)(ws + (96ull << 20));           // reuse down region

    k1_conv1x1<<<4096, 256, 0, stream>>>(x, w_in, out0);
    k2_vert  <<<256,  256, 0, stream>>>(out0, w_up, b_up, w_dn, b_dn, up, down);
    k2_horiz <<<256,  256, 0, stream>>>(out0, w_rt, b_rt, w_lf, b_lf, right, left);
    k3_mix   <<<4096, 256, 0, stream>>>(up, right, down, left, wD2, out3);
    conv3x3<64><<<1024, 256, 0, stream>>>(out3, a1w, a1b, a1);
    conv3x3<32><<<1024, 256, 0, stream>>>(a1, a2w, a2b, a2);
    k6_gate  <<<1024, 256, 0, stream>>>(a2, a3w, a3b, x, out);
}

// Round 3
// 538.227 us; speedup vs baseline: 1.6821x; 1.6821x over previous
//
#include <hip/hip_runtime.h>
#include <hip/hip_bf16.h>

#define HWSZ  65536

typedef unsigned short ushort_t;
typedef unsigned int   uint_t;
typedef __attribute__((ext_vector_type(8))) short short8;
typedef __attribute__((ext_vector_type(4))) float f32x4;

static __device__ __forceinline__ ushort_t f2bf(float f) {
    uint_t u = __float_as_uint(f);
    uint_t r = (u + 0x7fffu + ((u >> 16) & 1u)) >> 16;   // RNE
    return (ushort_t)r;
}
// v ~= hi + lo, each bf16 (total ~16 mantissa bits)
static __device__ __forceinline__ void split_bf(float v, ushort_t& hi, ushort_t& lo) {
    hi = f2bf(v);
    float hv = __uint_as_float((uint_t)hi << 16);
    lo = f2bf(v - hv);
}

// ---------------- K1: conv1x1 64->64 fp32, out0 channel-minor [pix][64] ----------------
__global__ __launch_bounds__(256) void k1_conv1x1(
    const float* __restrict__ x, const float* __restrict__ w_in,
    float* __restrict__ out0)
{
    __shared__ float xs[64][64];
    int b   = blockIdx.x >> 10;
    int hw0 = (blockIdx.x & 1023) << 6;
    const float* xb = x + ((size_t)b * 64) * HWSZ + hw0;

    for (int idx = threadIdx.x; idx < 1024; idx += 256) {
        int i = idx >> 4, p4 = (idx & 15) << 2;
        *(float4*)&xs[i][p4] = *(const float4*)(xb + (size_t)i * HWSZ + p4);
    }
    __syncthreads();

    int p  = threadIdx.x & 63;
    int og = __builtin_amdgcn_readfirstlane(threadIdx.x >> 6);
    float acc[16];
#pragma unroll
    for (int oo = 0; oo < 16; oo++) acc[oo] = 0.f;

#pragma unroll 8
    for (int i = 0; i < 64; i++) {
        float xv = xs[i][p];
#pragma unroll
        for (int oo = 0; oo < 16; oo++)
            acc[oo] += w_in[(og * 16 + oo) * 64 + i] * xv;   // scalar loads
    }
    float* ob = out0 + ((size_t)b * HWSZ + hw0 + p) * 64 + og * 16;
#pragma unroll
    for (int k = 0; k < 4; k++) {
        float4 v = {acc[4*k], acc[4*k+1], acc[4*k+2], acc[4*k+3]};
        *(float4*)(ob + 4*k) = v;
    }
}

// ---------------- K2: directional scans, one direction per block ----------------
// cat layout: [pix][256] = [up(0) | right(64) | down(128) | left(192)]
__global__ __launch_bounds__(256) void k2_scan(
    const float* __restrict__ out0,
    const float* __restrict__ w_up, const float* __restrict__ b_up,
    const float* __restrict__ w_rt, const float* __restrict__ b_rt,
    const float* __restrict__ w_dn, const float* __restrict__ b_dn,
    const float* __restrict__ w_lf, const float* __restrict__ b_lf,
    ushort_t* __restrict__ cat)
{
    int c = threadIdx.x & 63;
    int q = threadIdx.x >> 6;
    int dir = blockIdx.x >> 8;          // 0=down 1=up 2=right 3=left
    int bid = blockIdx.x & 255;
    int b = bid >> 6, g = bid & 63;
    int line = g * 4 + q;
    size_t base = (size_t)b * HWSZ;

    float wv, bv; int coff;
    if      (dir == 0) { wv = w_dn[c]; bv = b_dn[c]; coff = 128; }
    else if (dir == 1) { wv = w_up[c]; bv = b_up[c]; coff = 0;   }
    else if (dir == 2) { wv = w_rt[c]; bv = b_rt[c]; coff = 64;  }
    else               { wv = w_lf[c]; bv = b_lf[c]; coff = 192; }
    bool fwd  = (dir == 0) || (dir == 2);
    bool vert = (dir <= 1);

    float h = 0.f;
#pragma unroll 4
    for (int k = 0; k < 256; k++) {
        int i = fwd ? k : 255 - k;
        size_t pix = vert ? (base + i * 256 + line) : (base + line * 256 + i);
        float v = out0[pix * 64 + c];
        h = fmaxf(0.f, v + wv * h + bv);
        cat[pix * 256 + coff + c] = f2bf(h);
    }
}

// ---------------- packW: wD2 -> hi/lo bf16 planes, [o][256] ----------------
__global__ __launch_bounds__(256) void packw(const float* __restrict__ wD2,
                                             ushort_t* __restrict__ wh,
                                             ushort_t* __restrict__ wl)
{
    int i = blockIdx.x * 256 + threadIdx.x;   // 16384
    ushort_t h, l; split_bf(wD2[i], h, l);
    wh[i] = h; wl[i] = l;
}

// ---------------- packB: conv weights -> MFMA B-fragment order, hi/lo ----------------
// pbuf[((s*2+t)*64+lane)*8 + j]; oc = t*16+(lane&15); gk = s*32+(lane>>4)*8+j
// p1: 18432 elems (s<18); p2: 9216 elems (s<9)
__global__ __launch_bounds__(256) void packb(
    const float* __restrict__ a1w, const float* __restrict__ a2w,
    ushort_t* __restrict__ p1h, ushort_t* __restrict__ p1l,
    ushort_t* __restrict__ p2h, ushort_t* __restrict__ p2l)
{
    int i = blockIdx.x * 256 + threadIdx.x;   // 18432 + 9216 = 27648 -> grid 108
    if (i < 18432) {
        int j = i & 7, lane = (i >> 3) & 63, st = i >> 9;   // st in [0,36)
        int s = st >> 1, t = st & 1;
        int oc = t * 16 + (lane & 15);
        int gk = s * 32 + (lane >> 4) * 8 + j;
        int dydx = gk >> 6, ic = gk & 63;
        ushort_t h, l;
        split_bf(a1w[((oc * 64 + ic) * 3 + dydx / 3) * 3 + dydx % 3], h, l);
        p1h[i] = h; p1l[i] = l;
    } else if (i < 27648) {
        int e = i - 18432;
        int j = e & 7, lane = (e >> 3) & 63, st = e >> 9;    // st in [0,18)
        int s = st >> 1, t = st & 1;
        int oc = t * 16 + (lane & 15);
        int gk = s * 32 + (lane >> 4) * 8 + j;
        int dydx = gk >> 5, ic = gk & 31;
        ushort_t h, l;
        split_bf(a2w[((oc * 32 + ic) * 3 + dydx / 3) * 3 + dydx % 3], h, l);
        p2h[e] = h; p2l[e] = l;
    }
}

// ---------------- K3: MFMA GEMM  out3 = relu(cat @ wD2^T), hi/lo output planes ----------------
__global__ __launch_bounds__(256) void k3_mfma(
    const ushort_t* __restrict__ cat,
    const ushort_t* __restrict__ wh, const ushort_t* __restrict__ wl,
    ushort_t* __restrict__ o3h, ushort_t* __restrict__ o3l)
{
    int wave = threadIdx.x >> 6, lane = threadIdx.x & 63;
    int n16 = lane & 15, quad = lane >> 4;
    size_t p0 = (size_t)blockIdx.x * 64 + wave * 16;
    const ushort_t* aptr = cat + (p0 + n16) * 256 + quad * 8;

    f32x4 acc[4] = {};
#pragma unroll
    for (int s = 0; s < 8; s++) {
        short8 af = *(const short8*)(aptr + s * 32);
#pragma unroll
        for (int t = 0; t < 4; t++) {
            size_t wi = (size_t)(t * 16 + n16) * 256 + s * 32 + quad * 8;
            short8 bh = *(const short8*)(wh + wi);
            acc[t] = __builtin_amdgcn_mfma_f32_16x16x32_bf16(af, bh, acc[t], 0, 0, 0);
            short8 bl = *(const short8*)(wl + wi);
            acc[t] = __builtin_amdgcn_mfma_f32_16x16x32_bf16(af, bl, acc[t], 0, 0, 0);
        }
    }
#pragma unroll
    for (int t = 0; t < 4; t++)
#pragma unroll
        for (int r = 0; r < 4; r++) {
            size_t op = (p0 + quad * 4 + r) * 64 + t * 16 + n16;
            ushort_t h, l;
            split_bf(fmaxf(acc[t][r], 0.f), h, l);
            o3h[op] = h; o3l[op] = l;
        }
}

// ---------------- conv3x3 implicit-GEMM MFMA (IC -> 32), hi/lo in, bias+relu ----------------
template <int IC, bool SPLIT_OUT>
__global__ __launch_bounds__(256) void convmfma(
    const ushort_t* __restrict__ in_h, const ushort_t* __restrict__ in_l,
    const ushort_t* __restrict__ pbh, const ushort_t* __restrict__ pbl,
    const float* __restrict__ bias,
    ushort_t* __restrict__ oh, ushort_t* __restrict__ ol, float* __restrict__ of)
{
    constexpr int KS = IC * 9 / 32;     // 18 (IC=64) or 9 (IC=32)
    int wave = threadIdx.x >> 6, lane = threadIdx.x & 63;
    int n16 = lane & 15, quad = lane >> 4;
    int bid = blockIdx.x;
    int b = bid >> 10, rem = bid & 1023;
    int hh = rem >> 2;
    int w0 = (rem & 3) * 64 + wave * 16;
    int w  = w0 + n16;
    size_t boff = (size_t)b * HWSZ * IC;

    f32x4 acc[2] = {};
#pragma unroll
    for (int s = 0; s < KS; s++) {
        int gk0  = s * 32 + quad * 8;
        int dydx = gk0 / IC;            // lane-uniform within (s,quad); no IC-boundary cross
        int ic0  = gk0 - dydx * IC;
        int dy = dydx / 3 - 1, dx = dydx % 3 - 1;
        int gh = hh + dy, gw = w + dx;
        short8 ah = {}, al = {};
        if ((unsigned)gh < 256u && (unsigned)gw < 256u) {
            size_t ai = boff + ((size_t)(gh * 256 + gw)) * IC + ic0;
            ah = *(const short8*)(in_h + ai);
            al = *(const short8*)(in_l + ai);
        }
#pragma unroll
        for (int t = 0; t < 2; t++) {
            size_t wi = (size_t)((s * 2 + t) * 64 + lane) * 8;
            short8 bh = *(const short8*)(pbh + wi);
            short8 bl = *(const short8*)(pbl + wi);
            acc[t] = __builtin_amdgcn_mfma_f32_16x16x32_bf16(ah, bh, acc[t], 0, 0, 0);
            acc[t] = __builtin_amdgcn_mfma_f32_16x16x32_bf16(al, bh, acc[t], 0, 0, 0);
            acc[t] = __builtin_amdgcn_mfma_f32_16x16x32_bf16(ah, bl, acc[t], 0, 0, 0);
        }
    }
#pragma unroll
    for (int t = 0; t < 2; t++) {
        float bv = bias[t * 16 + n16];
#pragma unroll
        for (int r = 0; r < 4; r++) {
            int wp = w0 + quad * 4 + r;
            size_t op = ((size_t)b * HWSZ + hh * 256 + wp) * 32 + t * 16 + n16;
            float v = fmaxf(acc[t][r] + bv, 0.f);
            if (SPLIT_OUT) {
                ushort_t h, l; split_bf(v, h, l);
                oh[op] = h; ol[op] = l;
            } else {
                of[op] = v;
            }
        }
    }
}

// ---------------- K6: 1x1 (32->1) + sigmoid gate, a2 fp32 ----------------
__global__ __launch_bounds__(256) void k6_gate(
    const float* __restrict__ a2, const float* __restrict__ a3w,
    const float* __restrict__ a3b, const float* __restrict__ x,
    float* __restrict__ out)
{
    int pix = blockIdx.x * 256 + threadIdx.x;    // 262144
    int b = pix >> 16;
    int hw = pix & 65535;
    const float* ap = a2 + (size_t)pix * 32;
    float s = a3b[0];
#pragma unroll
    for (int k = 0; k < 8; k++) {
        float4 q = *(const float4*)(ap + k * 4);
        s += a3w[k*4+0] * q.x + a3w[k*4+1] * q.y + a3w[k*4+2] * q.z + a3w[k*4+3] * q.w;
    }
    float g = 1.f / (1.f + __expf(-s));
    const float* xb = x + (size_t)b * 64 * HWSZ + hw;
    float* ob = out + (size_t)b * 64 * HWSZ + hw;
#pragma unroll 8
    for (int c = 0; c < 64; c++)
        ob[(size_t)c * HWSZ] = fmaxf(0.f, xb[(size_t)c * HWSZ] * g);
}

extern "C" void kernel_launch(void* const* d_in, const int* in_sizes, int n_in,
                              void* d_out, int out_size, void* d_ws, size_t ws_size,
                              hipStream_t stream)
{
    const float* x     = (const float*)d_in[0];
    const float* w_in  = (const float*)d_in[1];
    const float* w_up  = (const float*)d_in[2];
    const float* b_up  = (const float*)d_in[3];
    const float* w_rt  = (const float*)d_in[4];
    const float* b_rt  = (const float*)d_in[5];
    const float* w_dn  = (const float*)d_in[6];
    const float* b_dn  = (const float*)d_in[7];
    const float* w_lf  = (const float*)d_in[8];
    const float* b_lf  = (const float*)d_in[9];
    const float* wD2   = (const float*)d_in[10];
    const float* a1w   = (const float*)d_in[11];
    const float* a1b   = (const float*)d_in[12];
    const float* a2w   = (const float*)d_in[13];
    const float* a2b   = (const float*)d_in[14];
    const float* a3w   = (const float*)d_in[15];
    const float* a3b   = (const float*)d_in[16];
    float* out = (float*)d_out;

    // Workspace timeline (<=192 MB):
    //  ws[0,64)MB : out0 fp32 [pix][64] (K1->K2); after K2 dead ->
    //               weight packs (packw/packb -> K3/conv1/conv2), tiny, at fixed offsets
    //  ws[64,192) : cat bf16 [pix][256] (K2->K3); after K3 dead ->
    //               a1_hi@64, a1_lo@80 (16 MB each), a2 fp32 @96..128 (conv1->conv2->K6)
    //  d_out      : out3_hi [pix][64] @0, out3_lo @+32MB (K3->conv1); overwritten by K6
    char* ws = (char*)d_ws;
    float*    out0 = (float*)ws;
    ushort_t* wh   = (ushort_t*)(ws);                          // 32 KB
    ushort_t* wl   = (ushort_t*)(ws + (256ull << 10));
    ushort_t* p1h  = (ushort_t*)(ws + (512ull << 10));         // 36 KB
    ushort_t* p1l  = (ushort_t*)(ws + (768ull << 10));
    ushort_t* p2h  = (ushort_t*)(ws + (1024ull << 10));        // 18 KB
    ushort_t* p2l  = (ushort_t*)(ws + (1280ull << 10));
    ushort_t* cat  = (ushort_t*)(ws + (64ull << 20));
    ushort_t* a1h  = (ushort_t*)(ws + (64ull << 20));          // alias cat (dead after K3)
    ushort_t* a1l  = (ushort_t*)(ws + (80ull << 20));
    float*    a2   = (float*)   (ws + (96ull << 20));
    ushort_t* o3h  = (ushort_t*)d_out;                         // 32 MB
    ushort_t* o3l  = o3h + (size_t)4 * HWSZ * 64;              // 32 MB

    k1_conv1x1<<<4096, 256, 0, stream>>>(x, w_in, out0);
    k2_scan   <<<1024, 256, 0, stream>>>(out0, w_up, b_up, w_rt, b_rt,
                                         w_dn, b_dn, w_lf, b_lf, cat);
    packw     <<<64,   256, 0, stream>>>(wD2, wh, wl);
    packb     <<<108,  256, 0, stream>>>(a1w, a2w, p1h, p1l, p2h, p2l);
    k3_mfma   <<<4096, 256, 0, stream>>>(cat, wh, wl, o3h, o3l);
    convmfma<64, true ><<<4096, 256, 0, stream>>>(o3h, o3l, p1h, p1l, a1b, a1h, a1l, nullptr);
    convmfma<32, false><<<4096, 256, 0, stream>>>(a1h, a1l, p2h, p2l, a2b, nullptr, nullptr, a2);
    k6_gate   <<<1024, 256, 0, stream>>>(a2, a3w, a3b, x, out);
}

// Round 4
// 426.900 us; speedup vs baseline: 2.1207x; 1.2608x over previous
//
#include <hip/hip_runtime.h>
#include <hip/hip_bf16.h>

#define HWSZ  65536

typedef unsigned short ushort_t;
typedef unsigned int   uint_t;
typedef __attribute__((ext_vector_type(8))) _Float16 half8;
typedef __attribute__((ext_vector_type(4))) float f32x4;

// ---------------- K1: conv1x1 64->64 fp32, out0 channel-minor [pix][64] ----------------
__global__ __launch_bounds__(256) void k1_conv1x1(
    const float* __restrict__ x, const float* __restrict__ w_in,
    float* __restrict__ out0)
{
    __shared__ float xs[64][64];
    int b   = blockIdx.x >> 10;
    int hw0 = (blockIdx.x & 1023) << 6;
    const float* xb = x + ((size_t)b * 64) * HWSZ + hw0;

    for (int idx = threadIdx.x; idx < 1024; idx += 256) {
        int i = idx >> 4, p4 = (idx & 15) << 2;
        *(float4*)&xs[i][p4] = *(const float4*)(xb + (size_t)i * HWSZ + p4);
    }
    __syncthreads();

    int p  = threadIdx.x & 63;
    int og = __builtin_amdgcn_readfirstlane(threadIdx.x >> 6);
    float acc[16];
#pragma unroll
    for (int oo = 0; oo < 16; oo++) acc[oo] = 0.f;

#pragma unroll 8
    for (int i = 0; i < 64; i++) {
        float xv = xs[i][p];
#pragma unroll
        for (int oo = 0; oo < 16; oo++)
            acc[oo] += w_in[(og * 16 + oo) * 64 + i] * xv;   // scalar loads
    }
    float* ob = out0 + ((size_t)b * HWSZ + hw0 + p) * 64 + og * 16;
#pragma unroll
    for (int k = 0; k < 4; k++) {
        float4 v = {acc[4*k], acc[4*k+1], acc[4*k+2], acc[4*k+3]};
        *(float4*)(ob + 4*k) = v;
    }
}

// ---------------- K2: directional scans, one direction per block, f16 out ----------------
// cat layout: [pix][256] = [up(0) | right(64) | down(128) | left(192)]
__global__ __launch_bounds__(256) void k2_scan(
    const float* __restrict__ out0,
    const float* __restrict__ w_up, const float* __restrict__ b_up,
    const float* __restrict__ w_rt, const float* __restrict__ b_rt,
    const float* __restrict__ w_dn, const float* __restrict__ b_dn,
    const float* __restrict__ w_lf, const float* __restrict__ b_lf,
    _Float16* __restrict__ cat)
{
    int c = threadIdx.x & 63;
    int q = threadIdx.x >> 6;
    int dir = blockIdx.x >> 8;          // 0=down 1=up 2=right 3=left
    int bid = blockIdx.x & 255;
    int b = bid >> 6, g = bid & 63;
    int line = g * 4 + q;
    size_t base = (size_t)b * HWSZ;

    float wv, bv; int coff;
    if      (dir == 0) { wv = w_dn[c]; bv = b_dn[c]; coff = 128; }
    else if (dir == 1) { wv = w_up[c]; bv = b_up[c]; coff = 0;   }
    else if (dir == 2) { wv = w_rt[c]; bv = b_rt[c]; coff = 64;  }
    else               { wv = w_lf[c]; bv = b_lf[c]; coff = 192; }
    bool fwd  = (dir == 0) || (dir == 2);
    bool vert = (dir <= 1);

    float h = 0.f;
#pragma unroll 4
    for (int k = 0; k < 256; k++) {
        int i = fwd ? k : 255 - k;
        size_t pix = vert ? (base + i * 256 + line) : (base + line * 256 + i);
        float v = out0[pix * 64 + c];
        h = fmaxf(0.f, v + wv * h + bv);
        cat[pix * 256 + coff + c] = (_Float16)h;
    }
}

// ---------------- packW: wD2 fp32 -> f16, [o][256] ----------------
__global__ __launch_bounds__(256) void packw(const float* __restrict__ wD2,
                                             _Float16* __restrict__ wf)
{
    int i = blockIdx.x * 256 + threadIdx.x;   // 16384
    wf[i] = (_Float16)wD2[i];
}

// ---------------- packB: conv weights -> MFMA B-fragment order, f16 ----------------
// pbuf[((s*2+t)*64+lane)*8 + j]; oc = t*16+(lane&15); gk = s*32+(lane>>4)*8+j
__global__ __launch_bounds__(256) void packb(
    const float* __restrict__ a1w, const float* __restrict__ a2w,
    _Float16* __restrict__ p1, _Float16* __restrict__ p2)
{
    int i = blockIdx.x * 256 + threadIdx.x;   // 18432 + 9216 = 27648 -> grid 108
    if (i < 18432) {
        int j = i & 7, lane = (i >> 3) & 63, st = i >> 9;   // st in [0,36)
        int s = st >> 1, t = st & 1;
        int oc = t * 16 + (lane & 15);
        int gk = s * 32 + (lane >> 4) * 8 + j;
        int dydx = gk >> 6, ic = gk & 63;
        p1[i] = (_Float16)a1w[((oc * 64 + ic) * 3 + dydx / 3) * 3 + dydx % 3];
    } else if (i < 27648) {
        int e = i - 18432;
        int j = e & 7, lane = (e >> 3) & 63, st = e >> 9;    // st in [0,18)
        int s = st >> 1, t = st & 1;
        int oc = t * 16 + (lane & 15);
        int gk = s * 32 + (lane >> 4) * 8 + j;
        int dydx = gk >> 5, ic = gk & 31;
        p2[e] = (_Float16)a2w[((oc * 32 + ic) * 3 + dydx / 3) * 3 + dydx % 3];
    }
}

// ---------------- K3: MFMA GEMM  out3[pix][64] = relu(cat[pix][256] @ wD2^T) ----------------
// Block = 64 pixels; wave w owns out-ch group t=w (16 ch), B in registers,
// A streamed via 12-deep rotating prefetch; 4 waves read identical A (L1 dedup).
__global__ __launch_bounds__(256) void k3_mfma(
    const _Float16* __restrict__ cat, const _Float16* __restrict__ wf,
    _Float16* __restrict__ out3)
{
    constexpr int DEPTH = 12, TOT = 32;      // 4 tiles x 8 s-steps
    int wave = threadIdx.x >> 6, lane = threadIdx.x & 63;
    int n16 = lane & 15, quad = lane >> 4;
    size_t p0 = (size_t)blockIdx.x * 64;
    const _Float16* abase = cat + (p0 + n16) * 256 + quad * 8;

    half8 B[8];
#pragma unroll
    for (int s = 0; s < 8; s++)
        B[s] = *(const half8*)(wf + (size_t)(wave * 16 + n16) * 256 + s * 32 + quad * 8);

    auto loadA = [&](int u) -> half8 {
        int j = u >> 3, s = u & 7;
        return *(const half8*)(abase + (size_t)j * 16 * 256 + s * 32);
    };

    f32x4 acc[4] = {};
    half8 abuf[DEPTH];
#pragma unroll
    for (int u = 0; u < DEPTH; u++) abuf[u] = loadA(u);
#pragma unroll
    for (int u = 0; u < TOT; u++) {
        half8 cur = abuf[u % DEPTH];
        if (u + DEPTH < TOT) abuf[u % DEPTH] = loadA(u + DEPTH);
        acc[u >> 3] = __builtin_amdgcn_mfma_f32_16x16x32_f16(cur, B[u & 7], acc[u >> 3], 0, 0, 0);
    }

#pragma unroll
    for (int j = 0; j < 4; j++)
#pragma unroll
        for (int r = 0; r < 4; r++) {
            size_t op = (p0 + j * 16 + quad * 4 + r) * 64 + wave * 16 + n16;
            out3[op] = (_Float16)fmaxf(acc[j][r], 0.f);
        }
}

// ---------------- conv3x3 implicit-GEMM MFMA (IC -> 32), bias+relu ----------------
// Block = 128 pixels (one row, 128 cols): wave = (half<<1)|t; waves t0/t1 share
// pixels (L1 dedup). B (KS x half8) in registers; A 12-deep rotating prefetch.
template <int IC, bool OUT_F32>
__global__ __launch_bounds__(256) void convmfma(
    const _Float16* __restrict__ in, const _Float16* __restrict__ pb,
    const float* __restrict__ bias,
    _Float16* __restrict__ oh, float* __restrict__ of)
{
    constexpr int KS = IC * 9 / 32;          // 18 or 9
    constexpr int NT = 4, TOT = NT * KS;
    constexpr int DEPTH = 12;
    int wave = threadIdx.x >> 6, lane = threadIdx.x & 63;
    int n16 = lane & 15, quad = lane >> 4;
    int t = wave & 1, half = wave >> 1;
    int bid = blockIdx.x;
    int b = bid >> 9;
    int hh = (bid >> 1) & 255;
    int w0 = ((bid & 1) << 1 | half) * 64;
    size_t ibase = (size_t)b * HWSZ * IC;

    half8 B[KS];
#pragma unroll
    for (int s = 0; s < KS; s++)
        B[s] = *(const half8*)(pb + (size_t)((s * 2 + t) * 64 + lane) * 8);

    auto loadA = [&](int u) -> half8 {
        int j = u / KS, s = u - (u / KS) * KS;
        int gk0 = s * 32 + quad * 8;
        int dydx = gk0 / IC;
        int ic0 = gk0 - dydx * IC;
        int dy = dydx / 3 - 1, dx = dydx % 3 - 1;
        int gh = hh + dy;
        int gw = w0 + j * 16 + n16 + dx;
        half8 a = {};
        if ((unsigned)gh < 256u && (unsigned)gw < 256u)
            a = *(const half8*)(in + ibase + ((size_t)(gh * 256 + gw)) * IC + ic0);
        return a;
    };

    f32x4 acc[NT] = {};
    half8 abuf[DEPTH];
#pragma unroll
    for (int u = 0; u < DEPTH; u++) abuf[u] = loadA(u);
#pragma unroll
    for (int u = 0; u < TOT; u++) {
        half8 cur = abuf[u % DEPTH];
        if (u + DEPTH < TOT) abuf[u % DEPTH] = loadA(u + DEPTH);
        int j = u / KS;
        acc[j] = __builtin_amdgcn_mfma_f32_16x16x32_f16(cur, B[u - j * KS], acc[j], 0, 0, 0);
    }

#pragma unroll
    for (int j = 0; j < NT; j++) {
        float bv = bias[t * 16 + n16];
#pragma unroll
        for (int r = 0; r < 4; r++) {
            int wp = w0 + j * 16 + quad * 4 + r;
            size_t op = ((size_t)b * HWSZ + hh * 256 + wp) * 32 + t * 16 + n16;
            float v = fmaxf(acc[j][r] + bv, 0.f);
            if (OUT_F32) of[op] = v; else oh[op] = (_Float16)v;
        }
    }
}

// ---------------- K6: 1x1 (32->1) + sigmoid gate, a2 fp32 ----------------
__global__ __launch_bounds__(256) void k6_gate(
    const float* __restrict__ a2, const float* __restrict__ a3w,
    const float* __restrict__ a3b, const float* __restrict__ x,
    float* __restrict__ out)
{
    int pix = blockIdx.x * 256 + threadIdx.x;    // 262144
    int b = pix >> 16;
    int hw = pix & 65535;
    const float* ap = a2 + (size_t)pix * 32;
    float s = a3b[0];
#pragma unroll
    for (int k = 0; k < 8; k++) {
        float4 q = *(const float4*)(ap + k * 4);
        s += a3w[k*4+0] * q.x + a3w[k*4+1] * q.y + a3w[k*4+2] * q.z + a3w[k*4+3] * q.w;
    }
    float g = 1.f / (1.f + __expf(-s));
    const float* xb = x + (size_t)b * 64 * HWSZ + hw;
    float* ob = out + (size_t)b * 64 * HWSZ + hw;
#pragma unroll 8
    for (int c = 0; c < 64; c++)
        ob[(size_t)c * HWSZ] = fmaxf(0.f, xb[(size_t)c * HWSZ] * g);
}

extern "C" void kernel_launch(void* const* d_in, const int* in_sizes, int n_in,
                              void* d_out, int out_size, void* d_ws, size_t ws_size,
                              hipStream_t stream)
{
    const float* x     = (const float*)d_in[0];
    const float* w_in  = (const float*)d_in[1];
    const float* w_up  = (const float*)d_in[2];
    const float* b_up  = (const float*)d_in[3];
    const float* w_rt  = (const float*)d_in[4];
    const float* b_rt  = (const float*)d_in[5];
    const float* w_dn  = (const float*)d_in[6];
    const float* b_dn  = (const float*)d_in[7];
    const float* w_lf  = (const float*)d_in[8];
    const float* b_lf  = (const float*)d_in[9];
    const float* wD2   = (const float*)d_in[10];
    const float* a1w   = (const float*)d_in[11];
    const float* a1b   = (const float*)d_in[12];
    const float* a2w   = (const float*)d_in[13];
    const float* a2b   = (const float*)d_in[14];
    const float* a3w   = (const float*)d_in[15];
    const float* a3b   = (const float*)d_in[16];
    float* out = (float*)d_out;

    // Workspace timeline (<=192 MB):
    //  ws[0,64)MB : out0 fp32 [pix][64]  (K1 -> K2). After K2 dead:
    //               out3 f16 [pix][64] @0 (32 MB, K3 -> conv1)
    //               wf16 @33MB (32KB), p1 @34MB (36KB), p2 @35MB (18KB)
    //  ws[64,192) : cat f16 [pix][256] (128 MB, K2 -> K3). After K3 dead:
    //               a1 f16 [pix][32] @64MB (16 MB, conv1 -> conv2)
    //               a2 fp32 [pix][32] @80MB (32 MB, conv2 -> K6)
    char* ws = (char*)d_ws;
    float*    out0 = (float*)ws;
    _Float16* out3 = (_Float16*)ws;
    _Float16* wf16 = (_Float16*)(ws + (33ull << 20));
    _Float16* p1   = (_Float16*)(ws + (34ull << 20));
    _Float16* p2   = (_Float16*)(ws + (35ull << 20));
    _Float16* cat  = (_Float16*)(ws + (64ull << 20));
    _Float16* a1   = (_Float16*)(ws + (64ull << 20));   // alias cat (dead after K3)
    float*    a2   = (float*)   (ws + (80ull << 20));

    k1_conv1x1<<<4096, 256, 0, stream>>>(x, w_in, out0);
    k2_scan   <<<1024, 256, 0, stream>>>(out0, w_up, b_up, w_rt, b_rt,
                                         w_dn, b_dn, w_lf, b_lf, cat);
    packw     <<<64,   256, 0, stream>>>(wD2, wf16);
    packb     <<<108,  256, 0, stream>>>(a1w, a2w, p1, p2);
    k3_mfma   <<<4096, 256, 0, stream>>>(cat, wf16, out3);
    convmfma<64, false><<<2048, 256, 0, stream>>>(out3, p1, a1b, a1, nullptr);
    convmfma<32, true ><<<2048, 256, 0, stream>>>(a1, p2, a2b, nullptr, a2);
    k6_gate   <<<1024, 256, 0, stream>>>(a2, a3w, a3b, x, out);
}

// Round 5
// 378.042 us; speedup vs baseline: 2.3948x; 1.1292x over previous
//
#include <hip/hip_runtime.h>
#include <hip/hip_bf16.h>

#define HWSZ  65536

typedef unsigned short ushort_t;
typedef unsigned int   uint_t;
typedef __attribute__((ext_vector_type(8))) _Float16 half8;
typedef __attribute__((ext_vector_type(4))) float f32x4;

// async global->LDS DMA, 16B per lane; LDS dst = wave-uniform base + lane*16
static __device__ __forceinline__ void gl_lds16(const void* g, void* l) {
    __builtin_amdgcn_global_load_lds(
        (const __attribute__((address_space(1))) unsigned int*)g,
        (__attribute__((address_space(3))) unsigned int*)l, 16, 0, 0);
}

// ---------------- K1: conv1x1 64->64 fp32, out0 channel-minor [pix][64] ----------------
__global__ __launch_bounds__(256) void k1_conv1x1(
    const float* __restrict__ x, const float* __restrict__ w_in,
    float* __restrict__ out0)
{
    __shared__ float xs[64][64];
    int b   = blockIdx.x >> 10;
    int hw0 = (blockIdx.x & 1023) << 6;
    const float* xb = x + ((size_t)b * 64) * HWSZ + hw0;

    for (int idx = threadIdx.x; idx < 1024; idx += 256) {
        int i = idx >> 4, p4 = (idx & 15) << 2;
        *(float4*)&xs[i][p4] = *(const float4*)(xb + (size_t)i * HWSZ + p4);
    }
    __syncthreads();

    int p  = threadIdx.x & 63;
    int og = __builtin_amdgcn_readfirstlane(threadIdx.x >> 6);
    float acc[16];
#pragma unroll
    for (int oo = 0; oo < 16; oo++) acc[oo] = 0.f;

#pragma unroll 8
    for (int i = 0; i < 64; i++) {
        float xv = xs[i][p];
#pragma unroll
        for (int oo = 0; oo < 16; oo++)
            acc[oo] += w_in[(og * 16 + oo) * 64 + i] * xv;   // scalar loads
    }
    float* ob = out0 + ((size_t)b * HWSZ + hw0 + p) * 64 + og * 16;
#pragma unroll
    for (int k = 0; k < 4; k++) {
        float4 v = {acc[4*k], acc[4*k+1], acc[4*k+2], acc[4*k+3]};
        *(float4*)(ob + 4*k) = v;
    }
}

// ---------------- K2: directional scans, one direction per block, f16 out ----------------
// cat layout: [pix][256] = [up(0) | right(64) | down(128) | left(192)]
__global__ __launch_bounds__(256) void k2_scan(
    const float* __restrict__ out0,
    const float* __restrict__ w_up, const float* __restrict__ b_up,
    const float* __restrict__ w_rt, const float* __restrict__ b_rt,
    const float* __restrict__ w_dn, const float* __restrict__ b_dn,
    const float* __restrict__ w_lf, const float* __restrict__ b_lf,
    _Float16* __restrict__ cat)
{
    int c = threadIdx.x & 63;
    int q = threadIdx.x >> 6;
    int dir = blockIdx.x >> 8;          // 0=down 1=up 2=right 3=left
    int bid = blockIdx.x & 255;
    int b = bid >> 6, g = bid & 63;
    int line = g * 4 + q;
    size_t base = (size_t)b * HWSZ;

    float wv, bv; int coff;
    if      (dir == 0) { wv = w_dn[c]; bv = b_dn[c]; coff = 128; }
    else if (dir == 1) { wv = w_up[c]; bv = b_up[c]; coff = 0;   }
    else if (dir == 2) { wv = w_rt[c]; bv = b_rt[c]; coff = 64;  }
    else               { wv = w_lf[c]; bv = b_lf[c]; coff = 192; }
    bool fwd  = (dir == 0) || (dir == 2);
    bool vert = (dir <= 1);

    float h = 0.f;
    for (int k0 = 0; k0 < 256; k0 += 8) {
        float v[8];
#pragma unroll
        for (int j = 0; j < 8; j++) {              // 8 independent loads batched
            int i = fwd ? (k0 + j) : 255 - (k0 + j);
            size_t pix = vert ? (base + i * 256 + line) : (base + line * 256 + i);
            v[j] = out0[pix * 64 + c];
        }
#pragma unroll
        for (int j = 0; j < 8; j++) {              // serial recurrence + store
            int i = fwd ? (k0 + j) : 255 - (k0 + j);
            size_t pix = vert ? (base + i * 256 + line) : (base + line * 256 + i);
            h = fmaxf(0.f, v[j] + wv * h + bv);
            cat[pix * 256 + coff + c] = (_Float16)h;
        }
    }
}

// ---------------- packW: wD2 fp32 -> f16, [o][256] ----------------
__global__ __launch_bounds__(256) void packw(const float* __restrict__ wD2,
                                             _Float16* __restrict__ wf)
{
    int i = blockIdx.x * 256 + threadIdx.x;   // 16384
    wf[i] = (_Float16)wD2[i];
}

// ---------------- packB: conv weights -> MFMA B-fragment order, f16 ----------------
__global__ __launch_bounds__(256) void packb(
    const float* __restrict__ a1w, const float* __restrict__ a2w,
    _Float16* __restrict__ p1, _Float16* __restrict__ p2)
{
    int i = blockIdx.x * 256 + threadIdx.x;   // 18432 + 9216 = 27648 -> grid 108
    if (i < 18432) {
        int j = i & 7, lane = (i >> 3) & 63, st = i >> 9;   // st in [0,36)
        int s = st >> 1, t = st & 1;
        int oc = t * 16 + (lane & 15);
        int gk = s * 32 + (lane >> 4) * 8 + j;
        int dydx = gk >> 6, ic = gk & 63;
        p1[i] = (_Float16)a1w[((oc * 64 + ic) * 3 + dydx / 3) * 3 + dydx % 3];
    } else if (i < 27648) {
        int e = i - 18432;
        int j = e & 7, lane = (e >> 3) & 63, st = e >> 9;    // st in [0,18)
        int s = st >> 1, t = st & 1;
        int oc = t * 16 + (lane & 15);
        int gk = s * 32 + (lane >> 4) * 8 + j;
        int dydx = gk >> 5, ic = gk & 31;
        p2[e] = (_Float16)a2w[((oc * 32 + ic) * 3 + dydx / 3) * 3 + dydx % 3];
    }
}

// ---------------- K3: LDS-staged MFMA GEMM  out3 = relu(cat @ wD2^T) ----------------
// m97 pattern: global_load_lds DMA -> barrier -> ds_read_b128 -> MFMA.
// 64-px tile, XOR-swizzled in the GLOBAL address (DMA LDS side is fixed lane*16).
__global__ __launch_bounds__(256) void k3_mfma(
    const _Float16* __restrict__ cat, const _Float16* __restrict__ wf,
    _Float16* __restrict__ out3)
{
    __shared__ _Float16 As[64 * 256];            // 32 KB
    int wave = threadIdx.x >> 6, lane = threadIdx.x & 63;
    int n16 = lane & 15, quad = lane >> 4;
    size_t p0 = (size_t)blockIdx.x * 64;

    // B: wave owns out-ch group wave*16 (8 x half8 = 32 VGPR)
    half8 B[8];
#pragma unroll
    for (int s = 0; s < 8; s++)
        B[s] = *(const half8*)(wf + (size_t)(wave * 16 + n16) * 256 + s * 32 + quad * 8);

    // Stage: wave stages local px [wave*16, wave*16+16). Iter it: 1024B = 2 rows.
    // Lane l: local px = wave*16 + it*2 + (l>>5); phys 16B-unit pu = l&31.
    // Swizzle: phys pu holds logical unit lu = pu ^ (px&7).
#pragma unroll
    for (int it = 0; it < 8; it++) {
        int px = wave * 16 + it * 2 + (lane >> 5);
        int pu = lane & 31;
        int lu = pu ^ (px & 7);
        const _Float16* gp = cat + ((p0 + px) << 8) + lu * 8;
        _Float16* lp = As + wave * 4096 + it * 512;          // wave-uniform base
        gl_lds16(gp, lp);
    }
    __syncthreads();

    f32x4 acc[4] = {};
#pragma unroll
    for (int j = 0; j < 4; j++) {
        int px = j * 16 + n16;
        const _Float16* lrow = As + px * 256;
        int x7 = px & 7;
#pragma unroll
        for (int s = 0; s < 8; s++) {
            int phys = (s * 4 + quad) ^ x7;                  // logical unit s*4+quad
            half8 a = *(const half8*)(lrow + phys * 8);
            acc[j] = __builtin_amdgcn_mfma_f32_16x16x32_f16(a, B[s], acc[j], 0, 0, 0);
        }
    }

#pragma unroll
    for (int j = 0; j < 4; j++)
#pragma unroll
        for (int r = 0; r < 4; r++) {
            size_t op = (p0 + j * 16 + quad * 4 + r) * 64 + wave * 16 + n16;
            out3[op] = (_Float16)fmaxf(acc[j][r], 0.f);
        }
}

// ---------------- conv3x3 implicit-GEMM MFMA (IC -> 32), bias+relu, f16 out ----------------
template <int IC>
__global__ __launch_bounds__(256) void convmfma(
    const _Float16* __restrict__ in, const _Float16* __restrict__ pb,
    const float* __restrict__ bias, _Float16* __restrict__ oh)
{
    constexpr int KS = IC * 9 / 32;          // 18 or 9
    constexpr int NT = 4, TOT = NT * KS;
    constexpr int DEPTH = 12;
    int wave = threadIdx.x >> 6, lane = threadIdx.x & 63;
    int n16 = lane & 15, quad = lane >> 4;
    int t = wave & 1, half = wave >> 1;
    int bid = blockIdx.x;
    int b = bid >> 9;
    int hh = (bid >> 1) & 255;
    int w0 = ((bid & 1) << 1 | half) * 64;
    size_t ibase = (size_t)b * HWSZ * IC;

    half8 B[KS];
#pragma unroll
    for (int s = 0; s < KS; s++)
        B[s] = *(const half8*)(pb + (size_t)((s * 2 + t) * 64 + lane) * 8);

    auto loadA = [&](int u) -> half8 {
        int j = u / KS, s = u - (u / KS) * KS;
        int gk0 = s * 32 + quad * 8;
        int dydx = gk0 / IC;
        int ic0 = gk0 - dydx * IC;
        int dy = dydx / 3 - 1, dx = dydx % 3 - 1;
        int gh = hh + dy;
        int gw = w0 + j * 16 + n16 + dx;
        half8 a = {};
        if ((unsigned)gh < 256u && (unsigned)gw < 256u)
            a = *(const half8*)(in + ibase + ((size_t)(gh * 256 + gw)) * IC + ic0);
        return a;
    };

    f32x4 acc[NT] = {};
    half8 abuf[DEPTH];
#pragma unroll
    for (int u = 0; u < DEPTH; u++) abuf[u] = loadA(u);
#pragma unroll
    for (int u = 0; u < TOT; u++) {
        half8 cur = abuf[u % DEPTH];
        if (u + DEPTH < TOT) abuf[u % DEPTH] = loadA(u + DEPTH);
        int j = u / KS;
        acc[j] = __builtin_amdgcn_mfma_f32_16x16x32_f16(cur, B[u - j * KS], acc[j], 0, 0, 0);
    }

#pragma unroll
    for (int j = 0; j < NT; j++) {
        float bv = bias[t * 16 + n16];
#pragma unroll
        for (int r = 0; r < 4; r++) {
            int wp = w0 + j * 16 + quad * 4 + r;
            size_t op = ((size_t)b * HWSZ + hh * 256 + wp) * 32 + t * 16 + n16;
            oh[op] = (_Float16)fmaxf(acc[j][r] + bv, 0.f);
        }
    }
}

// ---------------- K6: 1x1 (32->1) + sigmoid gate, a2 f16 ----------------
__global__ __launch_bounds__(256) void k6_gate(
    const _Float16* __restrict__ a2, const float* __restrict__ a3w,
    const float* __restrict__ a3b, const float* __restrict__ x,
    float* __restrict__ out)
{
    int pix = blockIdx.x * 256 + threadIdx.x;    // 262144
    int b = pix >> 16;
    int hw = pix & 65535;
    const _Float16* ap = a2 + (size_t)pix * 32;
    half8 q0 = *(const half8*)(ap);
    half8 q1 = *(const half8*)(ap + 8);
    half8 q2 = *(const half8*)(ap + 16);
    half8 q3 = *(const half8*)(ap + 24);
    float s = a3b[0];
#pragma unroll
    for (int j = 0; j < 8; j++) {
        s += a3w[j]      * (float)q0[j];
        s += a3w[j + 8]  * (float)q1[j];
        s += a3w[j + 16] * (float)q2[j];
        s += a3w[j + 24] * (float)q3[j];
    }
    float g = 1.f / (1.f + __expf(-s));
    const float* xb = x + (size_t)b * 64 * HWSZ + hw;
    float* ob = out + (size_t)b * 64 * HWSZ + hw;
#pragma unroll 8
    for (int c = 0; c < 64; c++)
        ob[(size_t)c * HWSZ] = fmaxf(0.f, xb[(size_t)c * HWSZ] * g);
}

extern "C" void kernel_launch(void* const* d_in, const int* in_sizes, int n_in,
                              void* d_out, int out_size, void* d_ws, size_t ws_size,
                              hipStream_t stream)
{
    const float* x     = (const float*)d_in[0];
    const float* w_in  = (const float*)d_in[1];
    const float* w_up  = (const float*)d_in[2];
    const float* b_up  = (const float*)d_in[3];
    const float* w_rt  = (const float*)d_in[4];
    const float* b_rt  = (const float*)d_in[5];
    const float* w_dn  = (const float*)d_in[6];
    const float* b_dn  = (const float*)d_in[7];
    const float* w_lf  = (const float*)d_in[8];
    const float* b_lf  = (const float*)d_in[9];
    const float* wD2   = (const float*)d_in[10];
    const float* a1w   = (const float*)d_in[11];
    const float* a1b   = (const float*)d_in[12];
    const float* a2w   = (const float*)d_in[13];
    const float* a2b   = (const float*)d_in[14];
    const float* a3w   = (const float*)d_in[15];
    const float* a3b   = (const float*)d_in[16];
    float* out = (float*)d_out;

    // Workspace timeline (<=192 MB):
    //  ws[0,64)MB : out0 fp32 [pix][64]  (K1 -> K2). After K2 dead:
    //               out3 f16 [pix][64] @0 (32 MB, K3 -> conv1)
    //               wf16 @33MB (32KB), p1 @34MB (36KB), p2 @35MB (18KB)
    //  ws[64,192) : cat f16 [pix][256] (128 MB, K2 -> K3). After K3 dead:
    //               a1 f16 [pix][32] @64MB (16 MB, conv1 -> conv2)
    //               a2 f16 [pix][32] @80MB (16 MB, conv2 -> K6)
    char* ws = (char*)d_ws;
    float*    out0 = (float*)ws;
    _Float16* out3 = (_Float16*)ws;
    _Float16* wf16 = (_Float16*)(ws + (33ull << 20));
    _Float16* p1   = (_Float16*)(ws + (34ull << 20));
    _Float16* p2   = (_Float16*)(ws + (35ull << 20));
    _Float16* cat  = (_Float16*)(ws + (64ull << 20));
    _Float16* a1   = (_Float16*)(ws + (64ull << 20));   // alias cat (dead after K3)
    _Float16* a2   = (_Float16*)(ws + (80ull << 20));

    k1_conv1x1<<<4096, 256, 0, stream>>>(x, w_in, out0);
    k2_scan   <<<1024, 256, 0, stream>>>(out0, w_up, b_up, w_rt, b_rt,
                                         w_dn, b_dn, w_lf, b_lf, cat);
    packw     <<<64,   256, 0, stream>>>(wD2, wf16);
    packb     <<<108,  256, 0, stream>>>(a1w, a2w, p1, p2);
    k3_mfma   <<<4096, 256, 0, stream>>>(cat, wf16, out3);
    convmfma<64><<<2048, 256, 0, stream>>>(out3, p1, a1b, a1);
    convmfma<32><<<2048, 256, 0, stream>>>(a1, p2, a2b, a2);
    k6_gate   <<<1024, 256, 0, stream>>>(a2, a3w, a3b, x, out);
}

// Round 6
// 322.651 us; speedup vs baseline: 2.8060x; 1.1717x over previous
//
#include <hip/hip_runtime.h>
#include <hip/hip_bf16.h>

#define HWSZ  65536

typedef unsigned short ushort_t;
typedef unsigned int   uint_t;
typedef __attribute__((ext_vector_type(8))) _Float16 half8;
typedef __attribute__((ext_vector_type(4))) float f32x4;

// async global->LDS DMA, 16B per lane; LDS dst = wave-uniform base + lane*16
static __device__ __forceinline__ void gl_lds16(const void* g, void* l) {
    __builtin_amdgcn_global_load_lds(
        (const __attribute__((address_space(1))) unsigned int*)g,
        (__attribute__((address_space(3))) unsigned int*)l, 16, 0, 0);
}

// ---------------- K1: conv1x1 64->64 fp32, out0 channel-minor [pix][64] ----------------
__global__ __launch_bounds__(256) void k1_conv1x1(
    const float* __restrict__ x, const float* __restrict__ w_in,
    float* __restrict__ out0)
{
    __shared__ float xs[64][64];
    int b   = blockIdx.x >> 10;
    int hw0 = (blockIdx.x & 1023) << 6;
    const float* xb = x + ((size_t)b * 64) * HWSZ + hw0;

    for (int idx = threadIdx.x; idx < 1024; idx += 256) {
        int i = idx >> 4, p4 = (idx & 15) << 2;
        *(float4*)&xs[i][p4] = *(const float4*)(xb + (size_t)i * HWSZ + p4);
    }
    __syncthreads();

    int p  = threadIdx.x & 63;
    int og = __builtin_amdgcn_readfirstlane(threadIdx.x >> 6);
    float acc[16];
#pragma unroll
    for (int oo = 0; oo < 16; oo++) acc[oo] = 0.f;

#pragma unroll 8
    for (int i = 0; i < 64; i++) {
        float xv = xs[i][p];
#pragma unroll
        for (int oo = 0; oo < 16; oo++)
            acc[oo] += w_in[(og * 16 + oo) * 64 + i] * xv;   // scalar loads
    }
    float* ob = out0 + ((size_t)b * HWSZ + hw0 + p) * 64 + og * 16;
#pragma unroll
    for (int k = 0; k < 4; k++) {
        float4 v = {acc[4*k], acc[4*k+1], acc[4*k+2], acc[4*k+3]};
        *(float4*)(ob + 4*k) = v;
    }
}

// ---------------- K2: directional scans, one direction per block, f16 out ----------------
// cat layout: [pix][256] = [up(0) | right(64) | down(128) | left(192)]
__global__ __launch_bounds__(256) void k2_scan(
    const float* __restrict__ out0,
    const float* __restrict__ w_up, const float* __restrict__ b_up,
    const float* __restrict__ w_rt, const float* __restrict__ b_rt,
    const float* __restrict__ w_dn, const float* __restrict__ b_dn,
    const float* __restrict__ w_lf, const float* __restrict__ b_lf,
    _Float16* __restrict__ cat)
{
    int c = threadIdx.x & 63;
    int q = threadIdx.x >> 6;
    int dir = blockIdx.x >> 8;          // 0=down 1=up 2=right 3=left
    int bid = blockIdx.x & 255;
    int b = bid >> 6, g = bid & 63;
    int line = g * 4 + q;
    size_t base = (size_t)b * HWSZ;

    float wv, bv; int coff;
    if      (dir == 0) { wv = w_dn[c]; bv = b_dn[c]; coff = 128; }
    else if (dir == 1) { wv = w_up[c]; bv = b_up[c]; coff = 0;   }
    else if (dir == 2) { wv = w_rt[c]; bv = b_rt[c]; coff = 64;  }
    else               { wv = w_lf[c]; bv = b_lf[c]; coff = 192; }
    bool fwd  = (dir == 0) || (dir == 2);
    bool vert = (dir <= 1);

    float h = 0.f;
    for (int k0 = 0; k0 < 256; k0 += 8) {
        float v[8];
#pragma unroll
        for (int j = 0; j < 8; j++) {              // 8 independent loads batched
            int i = fwd ? (k0 + j) : 255 - (k0 + j);
            size_t pix = vert ? (base + i * 256 + line) : (base + line * 256 + i);
            v[j] = out0[pix * 64 + c];
        }
#pragma unroll
        for (int j = 0; j < 8; j++) {              // serial recurrence + store
            int i = fwd ? (k0 + j) : 255 - (k0 + j);
            size_t pix = vert ? (base + i * 256 + line) : (base + line * 256 + i);
            h = fmaxf(0.f, v[j] + wv * h + bv);
            cat[pix * 256 + coff + c] = (_Float16)h;
        }
    }
}

// ---------------- packW: wD2 fp32 -> f16, [o][256] ----------------
__global__ __launch_bounds__(256) void packw(const float* __restrict__ wD2,
                                             _Float16* __restrict__ wf)
{
    int i = blockIdx.x * 256 + threadIdx.x;   // 16384
    wf[i] = (_Float16)wD2[i];
}

// ---------------- packB: conv weights -> MFMA B-fragment order, f16 ----------------
__global__ __launch_bounds__(256) void packb(
    const float* __restrict__ a1w, const float* __restrict__ a2w,
    _Float16* __restrict__ p1, _Float16* __restrict__ p2)
{
    int i = blockIdx.x * 256 + threadIdx.x;   // 18432 + 9216 = 27648 -> grid 108
    if (i < 18432) {
        int j = i & 7, lane = (i >> 3) & 63, st = i >> 9;   // st in [0,36)
        int s = st >> 1, t = st & 1;
        int oc = t * 16 + (lane & 15);
        int gk = s * 32 + (lane >> 4) * 8 + j;
        int dydx = gk >> 6, ic = gk & 63;
        p1[i] = (_Float16)a1w[((oc * 64 + ic) * 3 + dydx / 3) * 3 + dydx % 3];
    } else if (i < 27648) {
        int e = i - 18432;
        int j = e & 7, lane = (e >> 3) & 63, st = e >> 9;    // st in [0,18)
        int s = st >> 1, t = st & 1;
        int oc = t * 16 + (lane & 15);
        int gk = s * 32 + (lane >> 4) * 8 + j;
        int dydx = gk >> 5, ic = gk & 31;
        p2[e] = (_Float16)a2w[((oc * 32 + ic) * 3 + dydx / 3) * 3 + dydx % 3];
    }
}

// ---------------- K3: LDS-staged MFMA GEMM  out3 = relu(cat @ wD2^T) ----------------
__global__ __launch_bounds__(256) void k3_mfma(
    const _Float16* __restrict__ cat, const _Float16* __restrict__ wf,
    _Float16* __restrict__ out3)
{
    __shared__ _Float16 As[64 * 256];            // 32 KB
    int wave = threadIdx.x >> 6, lane = threadIdx.x & 63;
    int n16 = lane & 15, quad = lane >> 4;
    size_t p0 = (size_t)blockIdx.x * 64;

    half8 B[8];
#pragma unroll
    for (int s = 0; s < 8; s++)
        B[s] = *(const half8*)(wf + (size_t)(wave * 16 + n16) * 256 + s * 32 + quad * 8);

#pragma unroll
    for (int it = 0; it < 8; it++) {
        int px = wave * 16 + it * 2 + (lane >> 5);
        int pu = lane & 31;
        int lu = pu ^ (px & 7);
        const _Float16* gp = cat + ((p0 + px) << 8) + lu * 8;
        _Float16* lp = As + wave * 4096 + it * 512;          // wave-uniform base
        gl_lds16(gp, lp);
    }
    __syncthreads();

    f32x4 acc[4] = {};
#pragma unroll
    for (int j = 0; j < 4; j++) {
        int px = j * 16 + n16;
        const _Float16* lrow = As + px * 256;
        int x7 = px & 7;
#pragma unroll
        for (int s = 0; s < 8; s++) {
            int phys = (s * 4 + quad) ^ x7;
            half8 a = *(const half8*)(lrow + phys * 8);
            acc[j] = __builtin_amdgcn_mfma_f32_16x16x32_f16(a, B[s], acc[j], 0, 0, 0);
        }
    }

#pragma unroll
    for (int j = 0; j < 4; j++)
#pragma unroll
        for (int r = 0; r < 4; r++) {
            size_t op = (p0 + j * 16 + quad * 4 + r) * 64 + wave * 16 + n16;
            out3[op] = (_Float16)fmaxf(acc[j][r], 0.f);
        }
}

// ---------------- conv3x3: LDS-staged implicit-GEMM MFMA (IC -> 32), bias+relu ----------------
// Block: 4 out rows x 64 cols. LDS tile: 6 rows x 66 px x IC (halo incl).
// Central 64 px/row via global_load_lds DMA; halo cols + OOB rows via plain ds_write.
// IC=64: units swizzled by px&7 (else b128 reads hit only 16 banks); IC=32: no swizzle.
template <int IC>
__global__ __launch_bounds__(256) void convmfma(
    const _Float16* __restrict__ in, const _Float16* __restrict__ pb,
    const float* __restrict__ bias, _Float16* __restrict__ oh)
{
    constexpr int UPX = IC / 8;                  // 16B units per pixel
    constexpr int KST = IC / 32;                 // K-steps per (dy,dx)
    constexpr int PPS = 64 / UPX;                // pixels per 64-unit segment
    __shared__ _Float16 Ls[6 * 66 * IC];         // 50.7 KB (IC64) / 25.3 KB (IC32)

    int wave = threadIdx.x >> 6, lane = threadIdx.x & 63;
    int n16 = lane & 15, quad = lane >> 4;
    int bid = blockIdx.x;
    int bb  = bid >> 8;
    int hh0 = ((bid >> 2) & 63) << 2;
    int w0  = (bid & 3) << 6;
    const _Float16* ib = in + (size_t)bb * HWSZ * IC;

    // ---- stage central 6x64 px via DMA (row-OOB -> zero-fill) ----
#pragma unroll
    for (int it = 0; it < (6 * UPX) / 4; it++) {
        int q   = it * 4 + wave;                 // wave-segment id
        int r   = q / UPX, seg = q % UPX;
        int gh  = hh0 - 1 + r;
        int pxr = seg * PPS + lane / UPX;        // col-offset 0..63
        int pu  = lane % UPX;
        int px_lin = r * 66 + 1 + pxr;
        int lu  = (UPX == 8) ? (pu ^ (px_lin & 7)) : pu;
        _Float16* lp = Ls + (size_t)(r * 66 + 1 + seg * PPS) * IC;   // wave-uniform
        if ((unsigned)gh < 256u) {
            const _Float16* gp = ib + ((size_t)(gh * 256 + w0 + pxr)) * IC + lu * 8;
            gl_lds16(gp, lp);
        } else {
            half8 z = {};
            *(half8*)(lp + (size_t)lane * 8) = z;
        }
    }
    // ---- stage halo cols (px_lin col 0 and 65), 12 px x UPX units ----
    if (threadIdx.x < 12 * UPX) {
        int pu = threadIdx.x % UPX;
        int ph = threadIdx.x / UPX;              // 0..11
        int r = ph >> 1, side = ph & 1;
        int col = side ? 65 : 0;
        int gh = hh0 - 1 + r;
        int gw = w0 - 1 + side * 65;
        int px_lin = r * 66 + col;
        int lu = (UPX == 8) ? (pu ^ (px_lin & 7)) : pu;
        half8 v = {};
        if ((unsigned)gh < 256u && (unsigned)gw < 256u)
            v = *(const half8*)(ib + ((size_t)(gh * 256 + gw)) * IC + lu * 8);
        *(half8*)(Ls + (size_t)px_lin * IC + pu * 8) = v;
    }
    __syncthreads();

    // ---- compute: wave -> output row hh0+wave, 64 px x 32 oc ----
    f32x4 acc[4][2] = {};
#pragma unroll
    for (int dydx = 0; dydx < 9; dydx++) {
        int dy = dydx / 3, dx = dydx % 3;        // 0..2 (offset -1)
        int r_lds = wave + dy;
#pragma unroll
        for (int kst = 0; kst < KST; kst++) {
            int s = dydx * KST + kst;
            half8 B0 = *(const half8*)(pb + (size_t)((s * 2 + 0) * 64 + lane) * 8);
            half8 B1 = *(const half8*)(pb + (size_t)((s * 2 + 1) * 64 + lane) * 8);
            int u = kst * 4 + quad;              // IC=32: kst=0 -> u=quad
#pragma unroll
            for (int j = 0; j < 4; j++) {
                int px_lin = r_lds * 66 + j * 16 + n16 + dx;
                int phys = (UPX == 8) ? (u ^ (px_lin & 7)) : u;
                half8 A = *(const half8*)(Ls + (size_t)px_lin * IC + phys * 8);
                acc[j][0] = __builtin_amdgcn_mfma_f32_16x16x32_f16(A, B0, acc[j][0], 0, 0, 0);
                acc[j][1] = __builtin_amdgcn_mfma_f32_16x16x32_f16(A, B1, acc[j][1], 0, 0, 0);
            }
        }
    }

    int hh = hh0 + wave;
#pragma unroll
    for (int t = 0; t < 2; t++) {
        float bv = bias[t * 16 + n16];
#pragma unroll
        for (int j = 0; j < 4; j++)
#pragma unroll
            for (int r = 0; r < 4; r++) {
                int wp = w0 + j * 16 + quad * 4 + r;
                size_t op = ((size_t)bb * HWSZ + hh * 256 + wp) * 32 + t * 16 + n16;
                oh[op] = (_Float16)fmaxf(acc[j][t][r] + bv, 0.f);
            }
    }
}

// ---------------- K6: 1x1 (32->1) + sigmoid gate, a2 f16 ----------------
__global__ __launch_bounds__(256) void k6_gate(
    const _Float16* __restrict__ a2, const float* __restrict__ a3w,
    const float* __restrict__ a3b, const float* __restrict__ x,
    float* __restrict__ out)
{
    int pix = blockIdx.x * 256 + threadIdx.x;    // 262144
    int b = pix >> 16;
    int hw = pix & 65535;
    const _Float16* ap = a2 + (size_t)pix * 32;
    half8 q0 = *(const half8*)(ap);
    half8 q1 = *(const half8*)(ap + 8);
    half8 q2 = *(const half8*)(ap + 16);
    half8 q3 = *(const half8*)(ap + 24);
    float s = a3b[0];
#pragma unroll
    for (int j = 0; j < 8; j++) {
        s += a3w[j]      * (float)q0[j];
        s += a3w[j + 8]  * (float)q1[j];
        s += a3w[j + 16] * (float)q2[j];
        s += a3w[j + 24] * (float)q3[j];
    }
    float g = 1.f / (1.f + __expf(-s));
    const float* xb = x + (size_t)b * 64 * HWSZ + hw;
    float* ob = out + (size_t)b * 64 * HWSZ + hw;
#pragma unroll 8
    for (int c = 0; c < 64; c++)
        ob[(size_t)c * HWSZ] = fmaxf(0.f, xb[(size_t)c * HWSZ] * g);
}

extern "C" void kernel_launch(void* const* d_in, const int* in_sizes, int n_in,
                              void* d_out, int out_size, void* d_ws, size_t ws_size,
                              hipStream_t stream)
{
    const float* x     = (const float*)d_in[0];
    const float* w_in  = (const float*)d_in[1];
    const float* w_up  = (const float*)d_in[2];
    const float* b_up  = (const float*)d_in[3];
    const float* w_rt  = (const float*)d_in[4];
    const float* b_rt  = (const float*)d_in[5];
    const float* w_dn  = (const float*)d_in[6];
    const float* b_dn  = (const float*)d_in[7];
    const float* w_lf  = (const float*)d_in[8];
    const float* b_lf  = (const float*)d_in[9];
    const float* wD2   = (const float*)d_in[10];
    const float* a1w   = (const float*)d_in[11];
    const float* a1b   = (const float*)d_in[12];
    const float* a2w   = (const float*)d_in[13];
    const float* a2b   = (const float*)d_in[14];
    const float* a3w   = (const float*)d_in[15];
    const float* a3b   = (const float*)d_in[16];
    float* out = (float*)d_out;

    // Workspace timeline (<=192 MB):
    //  ws[0,64)MB : out0 fp32 [pix][64]  (K1 -> K2). After K2 dead:
    //               out3 f16 [pix][64] @0 (32 MB, K3 -> conv1)
    //               wf16 @33MB (32KB), p1 @34MB (36KB), p2 @35MB (18KB)
    //  ws[64,192) : cat f16 [pix][256] (128 MB, K2 -> K3). After K3 dead:
    //               a1 f16 [pix][32] @64MB (16 MB, conv1 -> conv2)
    //               a2 f16 [pix][32] @80MB (16 MB, conv2 -> K6)
    char* ws = (char*)d_ws;
    float*    out0 = (float*)ws;
    _Float16* out3 = (_Float16*)ws;
    _Float16* wf16 = (_Float16*)(ws + (33ull << 20));
    _Float16* p1   = (_Float16*)(ws + (34ull << 20));
    _Float16* p2   = (_Float16*)(ws + (35ull << 20));
    _Float16* cat  = (_Float16*)(ws + (64ull << 20));
    _Float16* a1   = (_Float16*)(ws + (64ull << 20));   // alias cat (dead after K3)
    _Float16* a2   = (_Float16*)(ws + (80ull << 20));

    k1_conv1x1<<<4096, 256, 0, stream>>>(x, w_in, out0);
    k2_scan   <<<1024, 256, 0, stream>>>(out0, w_up, b_up, w_rt, b_rt,
                                         w_dn, b_dn, w_lf, b_lf, cat);
    packw     <<<64,   256, 0, stream>>>(wD2, wf16);
    packb     <<<108,  256, 0, stream>>>(a1w, a2w, p1, p2);
    k3_mfma   <<<4096, 256, 0, stream>>>(cat, wf16, out3);
    convmfma<64><<<1024, 256, 0, stream>>>(out3, p1, a1b, a1);
    convmfma<32><<<1024, 256, 0, stream>>>(a1, p2, a2b, a2);
    k6_gate   <<<1024, 256, 0, stream>>>(a2, a3w, a3b, x, out);
}

// Round 7
// 277.787 us; speedup vs baseline: 3.2591x; 1.1615x over previous
//
#include <hip/hip_runtime.h>
#include <hip/hip_bf16.h>

#define HWSZ  65536

typedef unsigned short ushort_t;
typedef unsigned int   uint_t;
typedef __attribute__((ext_vector_type(8))) _Float16 half8;
typedef __attribute__((ext_vector_type(4))) float f32x4;

// async global->LDS DMA, 16B per lane; LDS dst = wave-uniform base + lane*16
static __device__ __forceinline__ void gl_lds16(const void* g, void* l) {
    __builtin_amdgcn_global_load_lds(
        (const __attribute__((address_space(1))) unsigned int*)g,
        (__attribute__((address_space(3))) unsigned int*)l, 16, 0, 0);
}

// ---------------- K1: conv1x1 64->64 via MFMA (f16 hi/lo = fp32-exact), out0 f16 ----------------
// LDS transpose: stage x [ic][px] tile, build A-frags [px][ic] via strided b32 reads.
__global__ __launch_bounds__(256) void k1_mfma(
    const float* __restrict__ x, const float* __restrict__ w_in,
    _Float16* __restrict__ out0)
{
    __shared__ float xs[64][64];                 // 16 KB, [ic][px]
    int b   = blockIdx.x >> 10;
    int hw0 = (blockIdx.x & 1023) << 6;
    const float* xb = x + ((size_t)b * 64) * HWSZ + hw0;
    int wave = threadIdx.x >> 6, lane = threadIdx.x & 63;
    int n16 = lane & 15, quad = lane >> 4;

    for (int idx = threadIdx.x; idx < 1024; idx += 256) {
        int i = idx >> 4, p4 = (idx & 15) << 2;
        *(float4*)&xs[i][p4] = *(const float4*)(xb + (size_t)i * HWSZ + p4);
    }

    // B-frags: wave owns oc group wave*16. B[n=oc][k=ic], w_in row-major in ic.
    half8 Bh[2], Bl[2];
#pragma unroll
    for (int s = 0; s < 2; s++) {
        const float* wp = w_in + (wave * 16 + n16) * 64 + s * 32 + quad * 8;
#pragma unroll
        for (int j = 0; j < 8; j++) {
            float v = wp[j];
            _Float16 h = (_Float16)v;
            float r = v - (float)h;
            Bh[s][j] = h; Bl[s][j] = (_Float16)r;
        }
    }
    __syncthreads();

    f32x4 acc[4] = {};
#pragma unroll
    for (int j = 0; j < 4; j++) {
#pragma unroll
        for (int s = 0; s < 2; s++) {
            half8 Ah, Al;
#pragma unroll
            for (int jj = 0; jj < 8; jj++) {     // strided LDS reads (transpose)
                float v = xs[s * 32 + quad * 8 + jj][j * 16 + n16];
                _Float16 h = (_Float16)v;
                float r = v - (float)h;
                Ah[jj] = h; Al[jj] = (_Float16)r;
            }
            acc[j] = __builtin_amdgcn_mfma_f32_16x16x32_f16(Ah, Bh[s], acc[j], 0, 0, 0);
            acc[j] = __builtin_amdgcn_mfma_f32_16x16x32_f16(Al, Bh[s], acc[j], 0, 0, 0);
            acc[j] = __builtin_amdgcn_mfma_f32_16x16x32_f16(Ah, Bl[s], acc[j], 0, 0, 0);
        }
    }
    _Float16* ob = out0 + ((size_t)b * HWSZ + hw0) * 64 + wave * 16;
#pragma unroll
    for (int j = 0; j < 4; j++)
#pragma unroll
        for (int r = 0; r < 4; r++) {
            int px = j * 16 + quad * 4 + r;      // C/D: row=quad*4+reg, col=n16
            ob[(size_t)px * 64 + n16] = (_Float16)acc[j][r];
        }
}

// ---------------- K2: paired directional scans (f16 in), f16 out ----------------
// cat layout: [pix][256] = [up(0) | right(64) | down(128) | left(192)]
__global__ __launch_bounds__(256) void k2_scan(
    const _Float16* __restrict__ out0,
    const float* __restrict__ w_up, const float* __restrict__ b_up,
    const float* __restrict__ w_rt, const float* __restrict__ b_rt,
    const float* __restrict__ w_dn, const float* __restrict__ b_dn,
    const float* __restrict__ w_lf, const float* __restrict__ b_lf,
    _Float16* __restrict__ cat)
{
    int c = threadIdx.x & 63;
    int q = threadIdx.x >> 6;
    bool vert = blockIdx.x < 256;
    int bid = blockIdx.x & 255;
    int b = bid >> 6, g = bid & 63;
    int line = g * 4 + q;
    size_t base = (size_t)b * HWSZ;

    float w0v, b0v, w1v, b1v; int coff0, coff1;
    if (vert) { w0v = w_dn[c]; b0v = b_dn[c]; coff0 = 128;
                w1v = w_up[c]; b1v = b_up[c]; coff1 = 0; }
    else      { w0v = w_rt[c]; b0v = b_rt[c]; coff0 = 64;
                w1v = w_lf[c]; b1v = b_lf[c]; coff1 = 192; }

#pragma unroll
    for (int pass = 0; pass < 2; pass++) {       // 0 = forward, 1 = backward
        float wv = pass ? w1v : w0v, bv = pass ? b1v : b0v;
        int coff = pass ? coff1 : coff0;
        float h = 0.f;
        for (int k0 = 0; k0 < 256; k0 += 8) {
            float v[8];
#pragma unroll
            for (int jx = 0; jx < 8; jx++) {     // 8 independent loads batched
                int i = pass ? 255 - (k0 + jx) : (k0 + jx);
                size_t pix = vert ? (base + i * 256 + line) : (base + line * 256 + i);
                v[jx] = (float)out0[pix * 64 + c];
            }
#pragma unroll
            for (int jx = 0; jx < 8; jx++) {     // serial recurrence + store
                int i = pass ? 255 - (k0 + jx) : (k0 + jx);
                size_t pix = vert ? (base + i * 256 + line) : (base + line * 256 + i);
                h = fmaxf(0.f, v[jx] + wv * h + bv);
                cat[pix * 256 + coff + c] = (_Float16)h;
            }
        }
    }
}

// ---------------- packW: wD2 fp32 -> f16, [o][256] ----------------
__global__ __launch_bounds__(256) void packw(const float* __restrict__ wD2,
                                             _Float16* __restrict__ wf)
{
    int i = blockIdx.x * 256 + threadIdx.x;   // 16384
    wf[i] = (_Float16)wD2[i];
}

// ---------------- packB: conv weights -> MFMA B-fragment order, f16 ----------------
__global__ __launch_bounds__(256) void packb(
    const float* __restrict__ a1w, const float* __restrict__ a2w,
    _Float16* __restrict__ p1, _Float16* __restrict__ p2)
{
    int i = blockIdx.x * 256 + threadIdx.x;   // 18432 + 9216 = 27648 -> grid 108
    if (i < 18432) {
        int j = i & 7, lane = (i >> 3) & 63, st = i >> 9;   // st in [0,36)
        int s = st >> 1, t = st & 1;
        int oc = t * 16 + (lane & 15);
        int gk = s * 32 + (lane >> 4) * 8 + j;
        int dydx = gk >> 6, ic = gk & 63;
        p1[i] = (_Float16)a1w[((oc * 64 + ic) * 3 + dydx / 3) * 3 + dydx % 3];
    } else if (i < 27648) {
        int e = i - 18432;
        int j = e & 7, lane = (e >> 3) & 63, st = e >> 9;    // st in [0,18)
        int s = st >> 1, t = st & 1;
        int oc = t * 16 + (lane & 15);
        int gk = s * 32 + (lane >> 4) * 8 + j;
        int dydx = gk >> 5, ic = gk & 31;
        p2[e] = (_Float16)a2w[((oc * 32 + ic) * 3 + dydx / 3) * 3 + dydx % 3];
    }
}

// ---------------- K3: LDS-staged MFMA GEMM  out3 = relu(cat @ wD2^T) ----------------
__global__ __launch_bounds__(256) void k3_mfma(
    const _Float16* __restrict__ cat, const _Float16* __restrict__ wf,
    _Float16* __restrict__ out3)
{
    __shared__ _Float16 As[64 * 256];            // 32 KB
    int wave = threadIdx.x >> 6, lane = threadIdx.x & 63;
    int n16 = lane & 15, quad = lane >> 4;
    size_t p0 = (size_t)blockIdx.x * 64;

    half8 B[8];
#pragma unroll
    for (int s = 0; s < 8; s++)
        B[s] = *(const half8*)(wf + (size_t)(wave * 16 + n16) * 256 + s * 32 + quad * 8);

#pragma unroll
    for (int it = 0; it < 8; it++) {
        int px = wave * 16 + it * 2 + (lane >> 5);
        int pu = lane & 31;
        int lu = pu ^ (px & 7);
        const _Float16* gp = cat + ((p0 + px) << 8) + lu * 8;
        _Float16* lp = As + wave * 4096 + it * 512;          // wave-uniform base
        gl_lds16(gp, lp);
    }
    __syncthreads();

    f32x4 acc[4] = {};
#pragma unroll
    for (int j = 0; j < 4; j++) {
        int px = j * 16 + n16;
        const _Float16* lrow = As + px * 256;
        int x7 = px & 7;
#pragma unroll
        for (int s = 0; s < 8; s++) {
            int phys = (s * 4 + quad) ^ x7;
            half8 a = *(const half8*)(lrow + phys * 8);
            acc[j] = __builtin_amdgcn_mfma_f32_16x16x32_f16(a, B[s], acc[j], 0, 0, 0);
        }
    }

#pragma unroll
    for (int j = 0; j < 4; j++)
#pragma unroll
        for (int r = 0; r < 4; r++) {
            size_t op = (p0 + j * 16 + quad * 4 + r) * 64 + wave * 16 + n16;
            out3[op] = (_Float16)fmaxf(acc[j][r], 0.f);
        }
}

// ---------------- conv3x3: LDS-staged implicit-GEMM MFMA (IC -> 32), bias+relu ----------------
template <int IC>
__global__ __launch_bounds__(256) void convmfma(
    const _Float16* __restrict__ in, const _Float16* __restrict__ pb,
    const float* __restrict__ bias, _Float16* __restrict__ oh)
{
    constexpr int UPX = IC / 8;                  // 16B units per pixel
    constexpr int KST = IC / 32;                 // K-steps per (dy,dx)
    constexpr int PPS = 64 / UPX;                // pixels per 64-unit segment
    __shared__ _Float16 Ls[6 * 66 * IC];

    int wave = threadIdx.x >> 6, lane = threadIdx.x & 63;
    int n16 = lane & 15, quad = lane >> 4;
    int bid = blockIdx.x;
    int bb  = bid >> 8;
    int hh0 = ((bid >> 2) & 63) << 2;
    int w0  = (bid & 3) << 6;
    const _Float16* ib = in + (size_t)bb * HWSZ * IC;

#pragma unroll
    for (int it = 0; it < (6 * UPX) / 4; it++) {
        int q   = it * 4 + wave;
        int r   = q / UPX, seg = q % UPX;
        int gh  = hh0 - 1 + r;
        int pxr = seg * PPS + lane / UPX;
        int pu  = lane % UPX;
        int px_lin = r * 66 + 1 + pxr;
        int lu  = (UPX == 8) ? (pu ^ (px_lin & 7)) : pu;
        _Float16* lp = Ls + (size_t)(r * 66 + 1 + seg * PPS) * IC;
        if ((unsigned)gh < 256u) {
            const _Float16* gp = ib + ((size_t)(gh * 256 + w0 + pxr)) * IC + lu * 8;
            gl_lds16(gp, lp);
        } else {
            half8 z = {};
            *(half8*)(lp + (size_t)lane * 8) = z;
        }
    }
    if (threadIdx.x < 12 * UPX) {
        int pu = threadIdx.x % UPX;
        int ph = threadIdx.x / UPX;
        int r = ph >> 1, side = ph & 1;
        int col = side ? 65 : 0;
        int gh = hh0 - 1 + r;
        int gw = w0 - 1 + side * 65;
        int px_lin = r * 66 + col;
        int lu = (UPX == 8) ? (pu ^ (px_lin & 7)) : pu;
        half8 v = {};
        if ((unsigned)gh < 256u && (unsigned)gw < 256u)
            v = *(const half8*)(ib + ((size_t)(gh * 256 + gw)) * IC + lu * 8);
        *(half8*)(Ls + (size_t)px_lin * IC + pu * 8) = v;
    }
    __syncthreads();

    f32x4 acc[4][2] = {};
#pragma unroll
    for (int dydx = 0; dydx < 9; dydx++) {
        int dy = dydx / 3, dx = dydx % 3;
        int r_lds = wave + dy;
#pragma unroll
        for (int kst = 0; kst < KST; kst++) {
            int s = dydx * KST + kst;
            half8 B0 = *(const half8*)(pb + (size_t)((s * 2 + 0) * 64 + lane) * 8);
            half8 B1 = *(const half8*)(pb + (size_t)((s * 2 + 1) * 64 + lane) * 8);
            int u = kst * 4 + quad;
#pragma unroll
            for (int j = 0; j < 4; j++) {
                int px_lin = r_lds * 66 + j * 16 + n16 + dx;
                int phys = (UPX == 8) ? (u ^ (px_lin & 7)) : u;
                half8 A = *(const half8*)(Ls + (size_t)px_lin * IC + phys * 8);
                acc[j][0] = __builtin_amdgcn_mfma_f32_16x16x32_f16(A, B0, acc[j][0], 0, 0, 0);
                acc[j][1] = __builtin_amdgcn_mfma_f32_16x16x32_f16(A, B1, acc[j][1], 0, 0, 0);
            }
        }
    }

    int hh = hh0 + wave;
#pragma unroll
    for (int t = 0; t < 2; t++) {
        float bv = bias[t * 16 + n16];
#pragma unroll
        for (int j = 0; j < 4; j++)
#pragma unroll
            for (int r = 0; r < 4; r++) {
                int wp = w0 + j * 16 + quad * 4 + r;
                size_t op = ((size_t)bb * HWSZ + hh * 256 + wp) * 32 + t * 16 + n16;
                oh[op] = (_Float16)fmaxf(acc[j][t][r] + bv, 0.f);
            }
    }
}

// ---------------- K6: 1x1 (32->1) + sigmoid gate, a2 f16 ----------------
__global__ __launch_bounds__(256) void k6_gate(
    const _Float16* __restrict__ a2, const float* __restrict__ a3w,
    const float* __restrict__ a3b, const float* __restrict__ x,
    float* __restrict__ out)
{
    int pix = blockIdx.x * 256 + threadIdx.x;    // 262144
    int b = pix >> 16;
    int hw = pix & 65535;
    const _Float16* ap = a2 + (size_t)pix * 32;
    half8 q0 = *(const half8*)(ap);
    half8 q1 = *(const half8*)(ap + 8);
    half8 q2 = *(const half8*)(ap + 16);
    half8 q3 = *(const half8*)(ap + 24);
    float s = a3b[0];
#pragma unroll
    for (int j = 0; j < 8; j++) {
        s += a3w[j]      * (float)q0[j];
        s += a3w[j + 8]  * (float)q1[j];
        s += a3w[j + 16] * (float)q2[j];
        s += a3w[j + 24] * (float)q3[j];
    }
    float g = 1.f / (1.f + __expf(-s));
    const float* xb = x + (size_t)b * 64 * HWSZ + hw;
    float* ob = out + (size_t)b * 64 * HWSZ + hw;
#pragma unroll 8
    for (int c = 0; c < 64; c++)
        ob[(size_t)c * HWSZ] = fmaxf(0.f, xb[(size_t)c * HWSZ] * g);
}

extern "C" void kernel_launch(void* const* d_in, const int* in_sizes, int n_in,
                              void* d_out, int out_size, void* d_ws, size_t ws_size,
                              hipStream_t stream)
{
    const float* x     = (const float*)d_in[0];
    const float* w_in  = (const float*)d_in[1];
    const float* w_up  = (const float*)d_in[2];
    const float* b_up  = (const float*)d_in[3];
    const float* w_rt  = (const float*)d_in[4];
    const float* b_rt  = (const float*)d_in[5];
    const float* w_dn  = (const float*)d_in[6];
    const float* b_dn  = (const float*)d_in[7];
    const float* w_lf  = (const float*)d_in[8];
    const float* b_lf  = (const float*)d_in[9];
    const float* wD2   = (const float*)d_in[10];
    const float* a1w   = (const float*)d_in[11];
    const float* a1b   = (const float*)d_in[12];
    const float* a2w   = (const float*)d_in[13];
    const float* a2b   = (const float*)d_in[14];
    const float* a3w   = (const float*)d_in[15];
    const float* a3b   = (const float*)d_in[16];
    float* out = (float*)d_out;

    // Workspace timeline (<=192 MB):
    //  ws[0,32)MB : out0 f16 [pix][64] (K1 -> K2); then out3 f16 (K3 -> conv1)
    //  ws@33/34/35MB : wf16 (32KB) / p1 (36KB) / p2 (18KB) weight packs
    //  ws[64,192) : cat f16 [pix][256] (K2 -> K3). After K3 dead:
    //               a1 f16 [pix][32] @64MB, a2 f16 [pix][32] @80MB
    char* ws = (char*)d_ws;
    _Float16* out0 = (_Float16*)ws;
    _Float16* out3 = (_Float16*)ws;
    _Float16* wf16 = (_Float16*)(ws + (33ull << 20));
    _Float16* p1   = (_Float16*)(ws + (34ull << 20));
    _Float16* p2   = (_Float16*)(ws + (35ull << 20));
    _Float16* cat  = (_Float16*)(ws + (64ull << 20));
    _Float16* a1   = (_Float16*)(ws + (64ull << 20));   // alias cat (dead after K3)
    _Float16* a2   = (_Float16*)(ws + (80ull << 20));

    k1_mfma   <<<4096, 256, 0, stream>>>(x, w_in, out0);
    k2_scan   <<<512,  256, 0, stream>>>(out0, w_up, b_up, w_rt, b_rt,
                                         w_dn, b_dn, w_lf, b_lf, cat);
    packw     <<<64,   256, 0, stream>>>(wD2, wf16);
    packb     <<<108,  256, 0, stream>>>(a1w, a2w, p1, p2);
    k3_mfma   <<<4096, 256, 0, stream>>>(cat, wf16, out3);
    convmfma<64><<<1024, 256, 0, stream>>>(out3, p1, a1b, a1);
    convmfma<32><<<1024, 256, 0, stream>>>(a1, p2, a2b, a2);
    k6_gate   <<<1024, 256, 0, stream>>>(a2, a3w, a3b, x, out);
}